// Round 4
// baseline (655.278 us; speedup 1.0000x reference)
//
#include <hip/hip_runtime.h>

#define D_NODE 128
#define D_EDGE 64
#define D_IN   192
#define NEG    0.01f
#define LN_EPS 1e-5f

typedef short bf16x8 __attribute__((ext_vector_type(8)));
typedef float f32x4  __attribute__((ext_vector_type(4)));

__device__ __forceinline__ unsigned f2bf(float f) {
    unsigned u = __builtin_bit_cast(unsigned, f);
    return (u + 0x7FFFu + ((u >> 16) & 1u)) >> 16;   // RNE
}
__device__ __forceinline__ unsigned pk2(float a, float b) {
    return f2bf(a) | (f2bf(b) << 16);
}
__device__ __forceinline__ float bf2f(unsigned short s) {
    unsigned u = ((unsigned)s) << 16;
    return __builtin_bit_cast(float, u);
}

// ---------------------------------------------------------------------------
// Preprocessing: hist -> atomic segment allocation -> bucket (perm only).
// Segment ORDER is irrelevant (only same-dest contiguity matters), so the
// exclusive scan is replaced by one atomicAdd-based allocator.
// ---------------------------------------------------------------------------
__global__ void k_hist(const int* __restrict__ ei, int* __restrict__ hist, int E) {
    int i = blockIdx.x * blockDim.x + threadIdx.x;
    int stride = gridDim.x * blockDim.x;
    for (int e = i; e < E; e += stride) atomicAdd(&hist[ei[E + e]], 1);
}

__global__ void k_alloc(const int* __restrict__ hist, int* __restrict__ base,
                        int* __restrict__ cursor, int N) {
    int i = blockIdx.x * blockDim.x + threadIdx.x;
    if (i < N) base[i] = atomicAdd(cursor, hist[i]);
}

__global__ void k_bucket(const int* __restrict__ ei, int* __restrict__ base,
                         int* __restrict__ perm, int E) {
    int i = blockIdx.x * blockDim.x + threadIdx.x;
    int stride = gridDim.x * blockDim.x;
    for (int e = i; e < E; e += stride) {
        int p = atomicAdd(&base[ei[E + e]], 1);
        perm[p] = e;
    }
}

// ---------------------------------------------------------------------------
// Edge kernel over dest-sorted edges, 64-edge tiles.
// A-fragments stored FRAGMENT-CONTIGUOUS in LDS: chunk for (et,kt,lane l) at
// ((et*6+kt)*64 + l)*8 ushorts -> lane l reads at l*16B: conflict-free b128.
// Staging: thread (e, qq) owns j-pair qq*2 of every 8-wide chunk (float2
// global loads, ds_write_b32 at bank 4*lm+qq = 2-way/free).
// Epilogue: y (bf16) into transposed yT[col][em] (aliased over Af),
// 4 r-values packed per ds_write_b64. Segmented reduce as round 3.
// ---------------------------------------------------------------------------
__global__ __launch_bounds__(256) void edge_mfma_seg(
    const float* __restrict__ x,
    const float* __restrict__ edge_attr,
    const int*   __restrict__ perm,
    const int*   __restrict__ edge_index,
    const float* __restrict__ W1,
    const float* __restrict__ b1,
    const float* __restrict__ g1,
    const float* __restrict__ be1,
    float* __restrict__ sums,
    int E, int ntiles)
{
    __shared__ unsigned short Af[12288];      // 24.6 KB A-frags; yT[128][68] aliases
    __shared__ float rS [64][4], rS2[64][4];
    __shared__ int   scol[64];
    __shared__ unsigned long long maskSh;
    unsigned short* const yT = Af;

    const int tid = threadIdx.x;
    const int w   = tid >> 6;
    const int l   = tid & 63;
    const int lm  = l & 15;
    const int q   = l >> 4;
    const int q8  = q * 8;

    // W1 fragments + LN params for this wave's 32 cols (once per block)
    bf16x8 Bfr[2][6];
    float  b1v[2], g1v[2], bev[2];
    #pragma unroll
    for (int c2 = 0; c2 < 2; ++c2) {
        const int n = (2 * w + c2) * 16 + lm;
        b1v[c2] = b1[n]; g1v[c2] = g1[n]; bev[c2] = be1[n];
        #pragma unroll
        for (int kt = 0; kt < 6; ++kt) {
            bf16x8 f;
            #pragma unroll
            for (int j = 0; j < 8; ++j)
                f[j] = (short)f2bf(W1[(kt * 32 + q8 + j) * 128 + n]);
            Bfr[c2][kt] = f;
        }
    }

    for (int tile = blockIdx.x; tile < ntiles; tile += gridDim.x) {
        const int e0 = tile * 64;

        // ---- stage A-fragments ----
        {
            const int e     = tid >> 2;          // edge in tile
            const int qq    = tid & 3;           // j-pair selector
            const int et    = e >> 4;
            const int elm   = e & 15;
            const int ge    = e0 + e;
            const int abase = et * 3072 + elm * 8 + qq * 2;
            if (ge < E) {
                const int eid = perm[ge];
                const int row = edge_index[eid];
                const float* xr = x + (size_t)row * D_NODE;
                const float* ar = edge_attr + (size_t)eid * D_EDGE;
                #pragma unroll
                for (int c = 0; c < 24; ++c) {   // chunk c: kt=c>>2, qf=c&3
                    const int k = c * 8 + qq * 2;
                    float2 v;
                    if (c < 16) v = *(const float2*)(xr + k);
                    else        v = *(const float2*)(ar + (k - 128));
                    *(unsigned*)&Af[abase + (c >> 2) * 512 + (c & 3) * 128] = pk2(v.x, v.y);
                }
            } else {
                #pragma unroll
                for (int c = 0; c < 24; ++c)
                    *(unsigned*)&Af[abase + (c >> 2) * 512 + (c & 3) * 128] = 0u;
            }
            if (tid < 64) {
                const int ge2 = e0 + tid;
                scol[tid] = (ge2 < E) ? edge_index[E + perm[ge2]] : -1;
            }
        }
        __syncthreads();                         // B1: Af/scol ready

        // ---- MFMA: 4 edge-tiles x 2 col-tiles, K=192 ----
        f32x4 acc[4][2];
        #pragma unroll
        for (int et = 0; et < 4; ++et)
            #pragma unroll
            for (int c2 = 0; c2 < 2; ++c2)
                acc[et][c2] = (f32x4){0.f, 0.f, 0.f, 0.f};

        #pragma unroll
        for (int et = 0; et < 4; ++et) {
            bf16x8 Afr[6];
            #pragma unroll
            for (int kt = 0; kt < 6; ++kt)
                Afr[kt] = *(const bf16x8*)&Af[et * 3072 + kt * 512 + l * 8];
            #pragma unroll
            for (int c2 = 0; c2 < 2; ++c2)
                #pragma unroll
                for (int kt = 0; kt < 6; ++kt)
                    acc[et][c2] = __builtin_amdgcn_mfma_f32_16x16x32_bf16(
                        Afr[kt], Bfr[c2][kt], acc[et][c2], 0, 0, 0);
        }

        // ---- bias + LN partial sums ----
        #pragma unroll
        for (int et = 0; et < 4; ++et) {
            #pragma unroll
            for (int r = 0; r < 4; ++r) {
                float v0 = acc[et][0][r] + b1v[0];
                float v1 = acc[et][1][r] + b1v[1];
                acc[et][0][r] = v0;
                acc[et][1][r] = v1;
                float s  = v0 + v1;
                float s2 = v0 * v0 + v1 * v1;
                #pragma unroll
                for (int off = 1; off < 16; off <<= 1) {
                    s  += __shfl_xor(s,  off, 16);
                    s2 += __shfl_xor(s2, off, 16);
                }
                if (lm == 0) {
                    const int em = et * 16 + q * 4 + r;
                    rS [em][w] = s;
                    rS2[em][w] = s2;
                }
            }
        }
        __syncthreads();                         // B2: rS ready; Af reads done

        // ---- run-start mask ----
        if (tid < 64) {
            int me = scol[tid];
            int pv = (tid == 0) ? (me ^ 1) : scol[tid - 1];
            unsigned long long m = __ballot(me != pv);
            if (tid == 0) maskSh = m;
        }

        // ---- finalize LN + LeakyReLU, y -> yT (bf16, b64-packed over r) ----
        #pragma unroll
        for (int et = 0; et < 4; ++et) {
            float mur[4], rsr[4];
            #pragma unroll
            for (int r = 0; r < 4; ++r) {
                const int em = et * 16 + q * 4 + r;
                float4 p  = *(const float4*)&rS [em][0];
                float4 p2 = *(const float4*)&rS2[em][0];
                const float S   = (p.x  + p.y)  + (p.z  + p.w);
                const float S2  = (p2.x + p2.y) + (p2.z + p2.w);
                const float mu  = S * (1.f / 128.f);
                const float var = S2 * (1.f / 128.f) - mu * mu;
                mur[r] = mu;
                rsr[r] = rsqrtf(var + LN_EPS);
            }
            #pragma unroll
            for (int c2 = 0; c2 < 2; ++c2) {
                unsigned short pkv[4];
                #pragma unroll
                for (int r = 0; r < 4; ++r) {
                    float y = (acc[et][c2][r] - mur[r]) * rsr[r] * g1v[c2] + bev[c2];
                    y = (y > 0.f) ? y : NEG * y;
                    pkv[r] = (unsigned short)f2bf(y);
                }
                const int col = (2 * w + c2) * 16 + lm;
                *(uint2*)&yT[col * 68 + et * 16 + q * 4] =
                    make_uint2((unsigned)pkv[0] | ((unsigned)pkv[1] << 16),
                               (unsigned)pkv[2] | ((unsigned)pkv[3] << 16));
            }
        }
        __syncthreads();                         // B3: yT + mask ready

        // ---- segmented reduce over dest runs ----
        {
            const unsigned long long mask = maskSh;
            const int g  = tid >> 7;
            const int j  = tid & 127;
            const int lo = g * 32;
            float s = 0.f;
            int rs = lo;
            #pragma unroll
            for (int i = 0; i < 32; ++i) {
                const int em = lo + i;
                s += bf2f(yT[j * 68 + em]);
                const int nx = em + 1;
                const bool isEnd = (i == 31) || ((mask >> nx) & 1ull);
                if (isEnd) {
                    const int dest = scol[em];
                    if (dest >= 0) {
                        const bool sg = (rs > 0) && ((mask >> rs) & 1ull);
                        const bool eg = (em < 63) && ((mask >> nx) & 1ull);
                        float* p = &sums[(size_t)dest * D_NODE + j];
                        if (sg && eg) *p = s;
                        else          atomicAdd(p, s);
                    }
                    s = 0.f; rs = nx;
                }
            }
        }
        __syncthreads();                         // B4: protect Af/yT/scol
    }
}

// ---------------------------------------------------------------------------
// Node kernel (MFMA): m = sums/cnt -> y = m@W2+b2 -> LN -> LeakyReLU
//                     -> +x -> LeakyReLU -> out.  64-node tiles.
// ---------------------------------------------------------------------------
__global__ __launch_bounds__(256) void node_mfma(
    const float* __restrict__ sums,
    const int*   __restrict__ hist,
    const float* __restrict__ x,
    const float* __restrict__ W2,
    const float* __restrict__ b2,
    const float* __restrict__ g2,
    const float* __restrict__ be2,
    float* __restrict__ out,
    int N)
{
    __shared__ unsigned short h[64][136];
    __shared__ float rS [64][4], rS2[64][4];

    const int tid = threadIdx.x;
    const int w   = tid >> 6;
    const int l   = tid & 63;
    const int lm  = l & 15;
    const int q   = l >> 4;
    const int q8  = q * 8;

    bf16x8 Bfr[2][4];
    float  b2v[2], g2v[2], bev[2];
    #pragma unroll
    for (int c2 = 0; c2 < 2; ++c2) {
        const int n = (2 * w + c2) * 16 + lm;
        b2v[c2] = b2[n]; g2v[c2] = g2[n]; bev[c2] = be2[n];
        #pragma unroll
        for (int kt = 0; kt < 4; ++kt) {
            bf16x8 f;
            #pragma unroll
            for (int j = 0; j < 8; ++j)
                f[j] = (short)f2bf(W2[(kt * 32 + q8 + j) * 128 + n]);
            Bfr[c2][kt] = f;
        }
    }

    const int n0 = blockIdx.x * 64;

    {
        const int e  = tid >> 2;
        const int qq = tid & 3;
        const int gn = n0 + e;
        if (gn < N) {
            const int cnt = hist[gn];
            const float sc = (cnt > 0) ? 1.f / (float)cnt : 0.f;
            const float4* sr = (const float4*)(sums + (size_t)gn * D_NODE);
            #pragma unroll
            for (int i = 0; i < 8; ++i) {
                float4 v = sr[qq * 8 + i];
                *(uint2*)&h[e][qq * 32 + i * 4] =
                    make_uint2(pk2(v.x * sc, v.y * sc), pk2(v.z * sc, v.w * sc));
            }
        } else {
            #pragma unroll
            for (int i = 0; i < 8; ++i)
                *(uint2*)&h[e][qq * 32 + i * 4] = make_uint2(0u, 0u);
        }
    }
    __syncthreads();

    f32x4 acc[4][2];
    #pragma unroll
    for (int et = 0; et < 4; ++et)
        #pragma unroll
        for (int c2 = 0; c2 < 2; ++c2)
            acc[et][c2] = (f32x4){0.f, 0.f, 0.f, 0.f};

    #pragma unroll
    for (int et = 0; et < 4; ++et) {
        bf16x8 Afr[4];
        #pragma unroll
        for (int kt = 0; kt < 4; ++kt)
            Afr[kt] = *(const bf16x8*)&h[et * 16 + lm][kt * 32 + q8];
        #pragma unroll
        for (int c2 = 0; c2 < 2; ++c2)
            #pragma unroll
            for (int kt = 0; kt < 4; ++kt)
                acc[et][c2] = __builtin_amdgcn_mfma_f32_16x16x32_bf16(
                    Afr[kt], Bfr[c2][kt], acc[et][c2], 0, 0, 0);
    }

    #pragma unroll
    for (int et = 0; et < 4; ++et) {
        #pragma unroll
        for (int r = 0; r < 4; ++r) {
            float v0 = acc[et][0][r] + b2v[0];
            float v1 = acc[et][1][r] + b2v[1];
            acc[et][0][r] = v0;
            acc[et][1][r] = v1;
            float s  = v0 + v1;
            float s2 = v0 * v0 + v1 * v1;
            #pragma unroll
            for (int off = 1; off < 16; off <<= 1) {
                s  += __shfl_xor(s,  off, 16);
                s2 += __shfl_xor(s2, off, 16);
            }
            if (lm == 0) {
                const int em = et * 16 + q * 4 + r;
                rS [em][w] = s;
                rS2[em][w] = s2;
            }
        }
    }
    __syncthreads();

    #pragma unroll
    for (int et = 0; et < 4; ++et) {
        #pragma unroll
        for (int r = 0; r < 4; ++r) {
            const int em = et * 16 + q * 4 + r;
            const int gn = n0 + em;
            if (gn >= N) continue;
            float4 p  = *(const float4*)&rS [em][0];
            float4 p2 = *(const float4*)&rS2[em][0];
            const float S    = (p.x  + p.y)  + (p.z  + p.w);
            const float S2   = (p2.x + p2.y) + (p2.z + p2.w);
            const float mu   = S * (1.f / 128.f);
            const float var  = S2 * (1.f / 128.f) - mu * mu;
            const float rstd = rsqrtf(var + LN_EPS);
            #pragma unroll
            for (int c2 = 0; c2 < 2; ++c2) {
                const int col = (2 * w + c2) * 16 + lm;
                float y = (acc[et][c2][r] - mu) * rstd * g2v[c2] + bev[c2];
                y = (y > 0.f) ? y : NEG * y;
                float rr = y + x[(size_t)gn * D_NODE + col];
                rr = (rr > 0.f) ? rr : NEG * rr;
                out[(size_t)gn * D_NODE + col] = rr;
            }
        }
    }
}

// ---------------------------------------------------------------------------
extern "C" void kernel_launch(void* const* d_in, const int* in_sizes, int n_in,
                              void* d_out, int out_size, void* d_ws, size_t ws_size,
                              hipStream_t stream) {
    const float* x          = (const float*)d_in[0];
    const int*   edge_index = (const int*)  d_in[1];
    const float* edge_attr  = (const float*)d_in[2];
    const float* W1         = (const float*)d_in[3];
    const float* b1         = (const float*)d_in[4];
    const float* g1         = (const float*)d_in[5];
    const float* be1        = (const float*)d_in[6];
    const float* W2         = (const float*)d_in[7];
    const float* b2         = (const float*)d_in[8];
    const float* g2         = (const float*)d_in[9];
    const float* be2        = (const float*)d_in[10];

    const int N = in_sizes[0] / D_NODE;     // 50000
    const int E = in_sizes[1] / 2;          // 600000

    float* sums   = (float*)d_ws;                       // N*128 f32
    int*   hist   = (int*)(sums + (size_t)N * D_NODE);  // N
    int*   cursor = hist + N;                           // 1
    int*   base   = cursor + 1;                         // N
    int*   perm   = base + N;                           // E

    // zero sums + hist + cursor in one shot
    hipMemsetAsync(d_ws, 0, ((size_t)N * D_NODE + N + 1) * sizeof(float), stream);

    k_hist  <<<dim3(512), dim3(256), 0, stream>>>(edge_index, hist, E);
    k_alloc <<<dim3((N + 255) / 256), dim3(256), 0, stream>>>(hist, base, cursor, N);
    k_bucket<<<dim3(512), dim3(256), 0, stream>>>(edge_index, base, perm, E);

    const int ntiles = (E + 63) / 64;
    const int grid   = ntiles < 1280 ? ntiles : 1280;
    edge_mfma_seg<<<dim3(grid), dim3(256), 0, stream>>>(
        x, edge_attr, perm, edge_index, W1, b1, g1, be1, sums, E, ntiles);

    node_mfma<<<dim3((N + 63) / 64), dim3(256), 0, stream>>>(
        sums, hist, x, W2, b2, g2, be2, (float*)d_out, N);
}

// Round 5
// 520.006 us; speedup vs baseline: 1.2601x; 1.2601x over previous
//
#include <hip/hip_runtime.h>

#define D_NODE 128
#define D_EDGE 64
#define D_IN   192
#define NEG    0.01f
#define LN_EPS 1e-5f

typedef short bf16x8 __attribute__((ext_vector_type(8)));
typedef float f32x4  __attribute__((ext_vector_type(4)));

__device__ __forceinline__ unsigned f2bf(float f) {
    unsigned u = __builtin_bit_cast(unsigned, f);
    return (u + 0x7FFFu + ((u >> 16) & 1u)) >> 16;   // RNE
}
__device__ __forceinline__ unsigned pk2(float a, float b) {
    return f2bf(a) | (f2bf(b) << 16);
}
__device__ __forceinline__ float bf2f(unsigned short s) {
    unsigned u = ((unsigned)s) << 16;
    return __builtin_bit_cast(float, u);
}

// ---------------------------------------------------------------------------
// Preprocessing: hist -> atomic segment allocation -> bucket.
// Segment ORDER is irrelevant (only same-dest contiguity matters), so the
// exclusive scan is one atomicAdd allocator. Bucket writes ONE packed 8 B
// record per sorted slot: {eid, row | col<<16}  (N=50000 < 2^16).
// ---------------------------------------------------------------------------
__global__ void k_hist(const int* __restrict__ ei, int* __restrict__ hist, int E) {
    int i = blockIdx.x * blockDim.x + threadIdx.x;
    int stride = gridDim.x * blockDim.x;
    for (int e = i; e < E; e += stride) atomicAdd(&hist[ei[E + e]], 1);
}

__global__ void k_alloc(const int* __restrict__ hist, int* __restrict__ base,
                        int* __restrict__ cursor, int N) {
    int i = blockIdx.x * blockDim.x + threadIdx.x;
    if (i < N) base[i] = atomicAdd(cursor, hist[i]);
}

__global__ void k_bucket(const int* __restrict__ ei, int* __restrict__ base,
                         uint2* __restrict__ recs, int E) {
    int i = blockIdx.x * blockDim.x + threadIdx.x;
    int stride = gridDim.x * blockDim.x;
    for (int e = i; e < E; e += stride) {
        int c = ei[E + e];
        int r = ei[e];
        int p = atomicAdd(&base[c], 1);
        recs[p] = make_uint2((unsigned)e, (unsigned)r | ((unsigned)c << 16));
    }
}

// ---------------------------------------------------------------------------
// Edge kernel over dest-sorted edges, 64-edge tiles (round-3 structure):
//   gather+concat (bf16 LDS, row-major h[64][200]) -> MFMA y = h@W1+b1
//   -> LN -> LeakyReLU -> y back into h (bf16) -> segmented sum over dest
//   runs: interior runs = plain store, boundary runs = atomicAdd.
// 256 threads = 4 waves; wave w owns cols [32w,32w+32); W1 frags in registers.
// NOTE: the 400 B row stride puts the 64-lane b128 A-read at its 8-cycle
// LDS floor (each bank serves exactly 8 dwords) — SQ_LDS_BANK_CONFLICT
// counts this but it is NOT improvable without losing b128/occupancy (R4).
// ---------------------------------------------------------------------------
__global__ __launch_bounds__(256) void edge_mfma_seg(
    const float* __restrict__ x,
    const float* __restrict__ edge_attr,
    const uint2* __restrict__ recs,
    const float* __restrict__ W1,
    const float* __restrict__ b1,
    const float* __restrict__ g1,
    const float* __restrict__ be1,
    float* __restrict__ sums,
    int E, int ntiles)
{
    __shared__ unsigned short h[64][200];     // 25.6 KB; also holds y (bf16) later
    __shared__ float rS [64][4], rS2[64][4];
    __shared__ int   scol[64];
    __shared__ unsigned long long maskSh;

    const int tid = threadIdx.x;
    const int w   = tid >> 6;
    const int l   = tid & 63;
    const int lm  = l & 15;
    const int q   = l >> 4;
    const int q8  = q * 8;

    // W1 fragments + LN params for this wave's 32 cols (once per block)
    bf16x8 Bfr[2][6];
    float  b1v[2], g1v[2], bev[2];
    #pragma unroll
    for (int c2 = 0; c2 < 2; ++c2) {
        const int n = (2 * w + c2) * 16 + lm;
        b1v[c2] = b1[n]; g1v[c2] = g1[n]; bev[c2] = be1[n];
        #pragma unroll
        for (int kt = 0; kt < 6; ++kt) {
            bf16x8 f;
            #pragma unroll
            for (int j = 0; j < 8; ++j)
                f[j] = (short)f2bf(W1[(kt * 32 + q8 + j) * 128 + n]);
            Bfr[c2][kt] = f;
        }
    }

    for (int tile = blockIdx.x; tile < ntiles; tile += gridDim.x) {
        const int e0 = tile * 64;

        // ---- stage h tile (gather + concat + fp32->bf16) ----
        {
            const int e  = tid >> 2;          // edge in tile
            const int qq = tid & 3;           // quarter of the row
            const int ge = e0 + e;
            if (ge < E) {
                const uint2 rc = recs[ge];
                const int eid = (int)rc.x;
                const int row = (int)(rc.y & 0xFFFFu);
                const float4* xr = (const float4*)(x + (size_t)row * D_NODE);
                #pragma unroll
                for (int i = 0; i < 8; ++i) {
                    float4 v = xr[qq * 8 + i];
                    *(uint2*)&h[e][qq * 32 + i * 4] =
                        make_uint2(pk2(v.x, v.y), pk2(v.z, v.w));
                }
                const float4* ar = (const float4*)(edge_attr + (size_t)eid * D_EDGE);
                #pragma unroll
                for (int i = 0; i < 4; ++i) {
                    float4 v = ar[qq * 4 + i];
                    *(uint2*)&h[e][128 + qq * 16 + i * 4] =
                        make_uint2(pk2(v.x, v.y), pk2(v.z, v.w));
                }
            } else {
                #pragma unroll
                for (int i = 0; i < 8; ++i)
                    *(uint2*)&h[e][qq * 32 + i * 4] = make_uint2(0u, 0u);
                #pragma unroll
                for (int i = 0; i < 4; ++i)
                    *(uint2*)&h[e][128 + qq * 16 + i * 4] = make_uint2(0u, 0u);
            }
            if (tid < 64)
                scol[tid] = (e0 + tid < E) ? (int)(recs[e0 + tid].y >> 16) : -1;
        }
        __syncthreads();                       // B1: h/scol ready

        // ---- MFMA: 4 edge-tiles x 2 col-tiles, K=192 ----
        f32x4 acc[4][2];
        #pragma unroll
        for (int et = 0; et < 4; ++et)
            #pragma unroll
            for (int c2 = 0; c2 < 2; ++c2)
                acc[et][c2] = (f32x4){0.f, 0.f, 0.f, 0.f};

        #pragma unroll
        for (int et = 0; et < 4; ++et) {
            bf16x8 Afr[6];
            #pragma unroll
            for (int kt = 0; kt < 6; ++kt)
                Afr[kt] = *(const bf16x8*)&h[et * 16 + lm][kt * 32 + q8];
            #pragma unroll
            for (int c2 = 0; c2 < 2; ++c2)
                #pragma unroll
                for (int kt = 0; kt < 6; ++kt)
                    acc[et][c2] = __builtin_amdgcn_mfma_f32_16x16x32_bf16(
                        Afr[kt], Bfr[c2][kt], acc[et][c2], 0, 0, 0);
        }

        // ---- bias + LN partial sums ----
        #pragma unroll
        for (int et = 0; et < 4; ++et) {
            #pragma unroll
            for (int r = 0; r < 4; ++r) {
                float v0 = acc[et][0][r] + b1v[0];
                float v1 = acc[et][1][r] + b1v[1];
                acc[et][0][r] = v0;
                acc[et][1][r] = v1;
                float s  = v0 + v1;
                float s2 = v0 * v0 + v1 * v1;
                #pragma unroll
                for (int off = 1; off < 16; off <<= 1) {
                    s  += __shfl_xor(s,  off, 16);
                    s2 += __shfl_xor(s2, off, 16);
                }
                if (lm == 0) {
                    const int em = et * 16 + q * 4 + r;
                    rS [em][w] = s;
                    rS2[em][w] = s2;
                }
            }
        }
        __syncthreads();                       // B2: rS ready; all h reads done

        // ---- run-start mask ----
        if (tid < 64) {
            int me = scol[tid];
            int pv = (tid == 0) ? (me ^ 1) : scol[tid - 1];
            unsigned long long m = __ballot(me != pv);
            if (tid == 0) maskSh = m;
        }

        // ---- finalize LN + LeakyReLU, write y (bf16) back into h ----
        #pragma unroll
        for (int et = 0; et < 4; ++et) {
            #pragma unroll
            for (int r = 0; r < 4; ++r) {
                const int em = et * 16 + q * 4 + r;
                float4 p  = *(const float4*)&rS [em][0];
                float4 p2 = *(const float4*)&rS2[em][0];
                const float S    = (p.x  + p.y)  + (p.z  + p.w);
                const float S2   = (p2.x + p2.y) + (p2.z + p2.w);
                const float mu   = S * (1.f / 128.f);
                const float var  = S2 * (1.f / 128.f) - mu * mu;
                const float rstd = rsqrtf(var + LN_EPS);
                #pragma unroll
                for (int c2 = 0; c2 < 2; ++c2) {
                    float y = (acc[et][c2][r] - mu) * rstd * g1v[c2] + bev[c2];
                    y = (y > 0.f) ? y : NEG * y;
                    h[em][(2 * w + c2) * 16 + lm] = (unsigned short)f2bf(y);
                }
            }
        }
        __syncthreads();                       // B3: y + mask ready

        // ---- segmented reduce over dest runs ----
        {
            const unsigned long long mask = maskSh;
            const int g  = tid >> 7;
            const int j  = tid & 127;
            const int lo = g * 32, hi = lo + 32;
            float s = 0.f;
            int rs = lo;
            for (int em = lo; em < hi; ++em) {
                s += bf2f(h[em][j]);
                const int nx = em + 1;
                const bool isEnd = (nx == hi) || ((mask >> nx) & 1ull);
                if (isEnd) {
                    const int dest = scol[em];
                    if (dest >= 0) {
                        const bool sg = (rs > 0) && ((mask >> rs) & 1ull);
                        const bool eg = (em < 63) && ((mask >> nx) & 1ull);
                        float* p = &sums[(size_t)dest * D_NODE + j];
                        if (sg && eg) *p = s;
                        else          atomicAdd(p, s);
                    }
                    s = 0.f; rs = nx;
                }
            }
        }
        __syncthreads();                       // B4: protect h/scol for next tile
    }
}

// ---------------------------------------------------------------------------
// Node kernel (MFMA): m = sums/cnt -> y = m@W2+b2 -> LN -> LeakyReLU
//                     -> +x -> LeakyReLU -> out.  64-node tiles.
// ---------------------------------------------------------------------------
__global__ __launch_bounds__(256) void node_mfma(
    const float* __restrict__ sums,
    const int*   __restrict__ hist,
    const float* __restrict__ x,
    const float* __restrict__ W2,
    const float* __restrict__ b2,
    const float* __restrict__ g2,
    const float* __restrict__ be2,
    float* __restrict__ out,
    int N)
{
    __shared__ unsigned short h[64][136];
    __shared__ float rS [64][4], rS2[64][4];

    const int tid = threadIdx.x;
    const int w   = tid >> 6;
    const int l   = tid & 63;
    const int lm  = l & 15;
    const int q   = l >> 4;
    const int q8  = q * 8;

    bf16x8 Bfr[2][4];
    float  b2v[2], g2v[2], bev[2];
    #pragma unroll
    for (int c2 = 0; c2 < 2; ++c2) {
        const int n = (2 * w + c2) * 16 + lm;
        b2v[c2] = b2[n]; g2v[c2] = g2[n]; bev[c2] = be2[n];
        #pragma unroll
        for (int kt = 0; kt < 4; ++kt) {
            bf16x8 f;
            #pragma unroll
            for (int j = 0; j < 8; ++j)
                f[j] = (short)f2bf(W2[(kt * 32 + q8 + j) * 128 + n]);
            Bfr[c2][kt] = f;
        }
    }

    const int n0 = blockIdx.x * 64;

    {
        const int e  = tid >> 2;
        const int qq = tid & 3;
        const int gn = n0 + e;
        if (gn < N) {
            const int cnt = hist[gn];
            const float sc = (cnt > 0) ? 1.f / (float)cnt : 0.f;
            const float4* sr = (const float4*)(sums + (size_t)gn * D_NODE);
            #pragma unroll
            for (int i = 0; i < 8; ++i) {
                float4 v = sr[qq * 8 + i];
                *(uint2*)&h[e][qq * 32 + i * 4] =
                    make_uint2(pk2(v.x * sc, v.y * sc), pk2(v.z * sc, v.w * sc));
            }
        } else {
            #pragma unroll
            for (int i = 0; i < 8; ++i)
                *(uint2*)&h[e][qq * 32 + i * 4] = make_uint2(0u, 0u);
        }
    }
    __syncthreads();

    f32x4 acc[4][2];
    #pragma unroll
    for (int et = 0; et < 4; ++et)
        #pragma unroll
        for (int c2 = 0; c2 < 2; ++c2)
            acc[et][c2] = (f32x4){0.f, 0.f, 0.f, 0.f};

    #pragma unroll
    for (int et = 0; et < 4; ++et) {
        bf16x8 Afr[4];
        #pragma unroll
        for (int kt = 0; kt < 4; ++kt)
            Afr[kt] = *(const bf16x8*)&h[et * 16 + lm][kt * 32 + q8];
        #pragma unroll
        for (int c2 = 0; c2 < 2; ++c2)
            #pragma unroll
            for (int kt = 0; kt < 4; ++kt)
                acc[et][c2] = __builtin_amdgcn_mfma_f32_16x16x32_bf16(
                    Afr[kt], Bfr[c2][kt], acc[et][c2], 0, 0, 0);
    }

    #pragma unroll
    for (int et = 0; et < 4; ++et) {
        #pragma unroll
        for (int r = 0; r < 4; ++r) {
            float v0 = acc[et][0][r] + b2v[0];
            float v1 = acc[et][1][r] + b2v[1];
            acc[et][0][r] = v0;
            acc[et][1][r] = v1;
            float s  = v0 + v1;
            float s2 = v0 * v0 + v1 * v1;
            #pragma unroll
            for (int off = 1; off < 16; off <<= 1) {
                s  += __shfl_xor(s,  off, 16);
                s2 += __shfl_xor(s2, off, 16);
            }
            if (lm == 0) {
                const int em = et * 16 + q * 4 + r;
                rS [em][w] = s;
                rS2[em][w] = s2;
            }
        }
    }
    __syncthreads();

    #pragma unroll
    for (int et = 0; et < 4; ++et) {
        #pragma unroll
        for (int r = 0; r < 4; ++r) {
            const int em = et * 16 + q * 4 + r;
            const int gn = n0 + em;
            if (gn >= N) continue;
            float4 p  = *(const float4*)&rS [em][0];
            float4 p2 = *(const float4*)&rS2[em][0];
            const float S    = (p.x  + p.y)  + (p.z  + p.w);
            const float S2   = (p2.x + p2.y) + (p2.z + p2.w);
            const float mu   = S * (1.f / 128.f);
            const float var  = S2 * (1.f / 128.f) - mu * mu;
            const float rstd = rsqrtf(var + LN_EPS);
            #pragma unroll
            for (int c2 = 0; c2 < 2; ++c2) {
                const int col = (2 * w + c2) * 16 + lm;
                float y = (acc[et][c2][r] - mu) * rstd * g2v[c2] + bev[c2];
                y = (y > 0.f) ? y : NEG * y;
                float rr = y + x[(size_t)gn * D_NODE + col];
                rr = (rr > 0.f) ? rr : NEG * rr;
                out[(size_t)gn * D_NODE + col] = rr;
            }
        }
    }
}

// ---------------------------------------------------------------------------
extern "C" void kernel_launch(void* const* d_in, const int* in_sizes, int n_in,
                              void* d_out, int out_size, void* d_ws, size_t ws_size,
                              hipStream_t stream) {
    const float* x          = (const float*)d_in[0];
    const int*   edge_index = (const int*)  d_in[1];
    const float* edge_attr  = (const float*)d_in[2];
    const float* W1         = (const float*)d_in[3];
    const float* b1         = (const float*)d_in[4];
    const float* g1         = (const float*)d_in[5];
    const float* be1        = (const float*)d_in[6];
    const float* W2         = (const float*)d_in[7];
    const float* b2         = (const float*)d_in[8];
    const float* g2         = (const float*)d_in[9];
    const float* be2        = (const float*)d_in[10];

    const int N = in_sizes[0] / D_NODE;     // 50000  (< 65536: rec packing)
    const int E = in_sizes[1] / 2;          // 600000

    // ws layout: recs (E uint2) | sums (N*128 f32) | hist (N) | cursor | base (N)
    uint2* recs   = (uint2*)d_ws;
    float* sums   = (float*)(recs + E);
    int*   hist   = (int*)(sums + (size_t)N * D_NODE);
    int*   cursor = hist + N;
    int*   base   = cursor + 1;

    // zero sums + hist + cursor in one shot (base written by k_alloc)
    hipMemsetAsync(sums, 0, ((size_t)N * D_NODE + N + 1) * sizeof(float), stream);

    k_hist  <<<dim3(512), dim3(256), 0, stream>>>(edge_index, hist, E);
    k_alloc <<<dim3((N + 255) / 256), dim3(256), 0, stream>>>(hist, base, cursor, N);
    k_bucket<<<dim3(512), dim3(256), 0, stream>>>(edge_index, base, recs, E);

    const int ntiles = (E + 63) / 64;
    const int grid   = ntiles < 1280 ? ntiles : 1280;   // 5 blocks/CU (LDS-limited)
    edge_mfma_seg<<<dim3(grid), dim3(256), 0, stream>>>(
        x, edge_attr, recs, W1, b1, g1, be1, sums, E, ntiles);

    node_mfma<<<dim3((N + 63) / 64), dim3(256), 0, stream>>>(
        sums, hist, x, W2, b2, g2, be2, (float*)d_out, N);
}